// Round 4
// baseline (536.771 us; speedup 1.0000x reference)
//
#include <hip/hip_runtime.h>

#define K 7
#define PAD 3
#define TH 8
#define LH (TH + 2 * PAD)   // 14 staged rows
#define LSTRIDE 520         // floats per LDS row (16B-aligned rows)
// LDS col layout per row: [0..3]=zero pad, [4..515]=sal, [516..519]=zero pad
// (horizontal halo at full-row stripes is always out-of-bounds -> zero)

typedef float f32x4 __attribute__((ext_vector_type(4)));

constexpr int H_ = 512, W_ = 512, HW_ = H_ * W_, K2 = K * K;

__global__ __launch_bounds__(1024) void adaptive_aggregation_kernel(
    const float* __restrict__ thick,
    const float* __restrict__ thin,
    const float* __restrict__ coeff,
    float* __restrict__ out)
{
    __shared__ float sal[LH][LSTRIDE];   // 29.1 KB

    const int b  = blockIdx.y;
    const int h0 = blockIdx.x * TH;
    const int tx = threadIdx.x;          // 0..127
    const int ty = threadIdx.y;          // 0..7
    const int tid = ty * 128 + tx;
    const size_t base1 = (size_t)b * HW_;

    // ---- zero the 8 horizontal-halo floats of each row (f32x4 writes) ----
    if (tid < LH * 2) {
        const int r = tid >> 1;
        const int c = (tid & 1) ? (LSTRIDE - 4) : 0;
        *reinterpret_cast<f32x4*>(&sal[r][c]) = (f32x4)0.f;
    }

    // ---- stage sal = max(thick,thin): fully coalesced float4, 2 passes ----
    #pragma unroll
    for (int pass = 0; pass < 2; ++pass) {
        const int r = pass * 8 + ty;
        if (r < LH) {
            const int gh = h0 - PAD + r;
            f32x4 v = (f32x4)0.f;
            if (gh >= 0 && gh < H_) {
                const size_t off = base1 + (size_t)gh * W_ + tx * 4;
                const f32x4 a = *reinterpret_cast<const f32x4*>(thick + off);
                const f32x4 t = *reinterpret_cast<const f32x4*>(thin + off);
                v.x = fmaxf(a.x, t.x);
                v.y = fmaxf(a.y, t.y);
                v.z = fmaxf(a.z, t.z);
                v.w = fmaxf(a.w, t.w);
            }
            *reinterpret_cast<f32x4*>(&sal[r][4 + tx * 4]) = v;  // 16B aligned
        }
    }
    __syncthreads();

    // ---- each thread: 4 consecutive output pixels at (h0+ty, tx*4 ..+3) ----
    const int h = h0 + ty;
    const int w4 = tx * 4;
    // compile-time plane stride: all 49 offsets are constants
    const float* cptr = coeff + (size_t)b * (K2 * HW_) + h * W_ + w4;

    float acc0 = 0.f, acc1 = 0.f, acc2 = 0.f, acc3 = 0.f;

    #pragma unroll
    for (int i = 0; i < K; ++i) {
        // sal cols (w4+1+c), c=0..9: covers j=0..6 for pixels p=0..3
        float row[K + 3];
        #pragma unroll
        for (int c = 0; c < K + 3; ++c)
            row[c] = sal[ty + i][w4 + 1 + c];

        #pragma unroll
        for (int j = 0; j < K; ++j) {
            const f32x4 c4 =
                *reinterpret_cast<const f32x4*>(cptr + (i * K + j) * HW_);
            acc0 = fmaf(row[j + 0], c4.x, acc0);
            acc1 = fmaf(row[j + 1], c4.y, acc1);
            acc2 = fmaf(row[j + 2], c4.z, acc2);
            acc3 = fmaf(row[j + 3], c4.w, acc3);
        }
    }

    f32x4 o;
    o.x = acc0; o.y = acc1; o.z = acc2; o.w = acc3;
    *reinterpret_cast<f32x4*>(out + base1 + (size_t)h * W_ + w4) = o;
}

extern "C" void kernel_launch(void* const* d_in, const int* in_sizes, int n_in,
                              void* d_out, int out_size, void* d_ws, size_t ws_size,
                              hipStream_t stream) {
    const float* thick = (const float*)d_in[0];
    const float* thin  = (const float*)d_in[1];
    const float* coeff = (const float*)d_in[2];
    float* out = (float*)d_out;

    const int B = in_sizes[0] / HW_;       // 8

    dim3 grid(H_ / TH, B);                 // (64, 8) = 512 blocks
    dim3 block(128, 8);                    // 1024 threads = 16 waves

    hipLaunchKernelGGL(adaptive_aggregation_kernel, grid, block, 0, stream,
                       thick, thin, coeff, out);
}

// Round 6
// 512.143 us; speedup vs baseline: 1.0481x; 1.0481x over previous
//
#include <hip/hip_runtime.h>

#define K 7
#define PAD 3
#define TH 8
#define LH (TH + 2 * PAD)   // 14 staged rows
#define LSTRIDE 520         // floats per LDS row (16B-aligned rows)
// LDS col layout per row: [0..3]=zero pad, [4..515]=sal, [516..519]=zero pad
// (horizontal halo at full-row stripes is always out-of-bounds -> zero)

typedef float f32x4 __attribute__((ext_vector_type(4)));

constexpr int H_ = 512, W_ = 512, HW_ = H_ * W_, K2 = K * K;

__global__ __launch_bounds__(1024) void adaptive_aggregation_kernel(
    const float* __restrict__ thick,
    const float* __restrict__ thin,
    const float* __restrict__ coeff,
    float* __restrict__ out)
{
    __shared__ float sal[LH][LSTRIDE];   // 29.1 KB

    const int b  = blockIdx.y;
    const int h0 = blockIdx.x * TH;
    const int tx = threadIdx.x;          // 0..127
    const int ty = threadIdx.y;          // 0..7
    const int tid = ty * 128 + tx;
    const size_t base1 = (size_t)b * HW_;

    // ---- zero the 8 horizontal-halo floats of each row (f32x4 writes) ----
    if (tid < LH * 2) {
        const int r = tid >> 1;
        const int c = (tid & 1) ? (LSTRIDE - 4) : 0;
        *reinterpret_cast<f32x4*>(&sal[r][c]) = (f32x4)0.f;
    }

    // ---- stage sal = max(thick,thin): fully coalesced float4, 2 passes ----
    #pragma unroll
    for (int pass = 0; pass < 2; ++pass) {
        const int r = pass * 8 + ty;
        if (r < LH) {
            const int gh = h0 - PAD + r;
            f32x4 v = (f32x4)0.f;
            if (gh >= 0 && gh < H_) {
                const size_t off = base1 + (size_t)gh * W_ + tx * 4;
                const f32x4 a = *reinterpret_cast<const f32x4*>(thick + off);
                const f32x4 t = *reinterpret_cast<const f32x4*>(thin + off);
                v.x = fmaxf(a.x, t.x);
                v.y = fmaxf(a.y, t.y);
                v.z = fmaxf(a.z, t.z);
                v.w = fmaxf(a.w, t.w);
            }
            *reinterpret_cast<f32x4*>(&sal[r][4 + tx * 4]) = v;  // 16B aligned
        }
    }
    __syncthreads();

    // ---- each thread: 4 consecutive output pixels at (h0+ty, tx*4 ..+3) ----
    const int h = h0 + ty;
    const int w4 = tx * 4;
    // compile-time plane stride: all 49 offsets are constants
    const float* cptr = coeff + (size_t)b * (K2 * HW_) + h * W_ + w4;

    float acc0 = 0.f, acc1 = 0.f, acc2 = 0.f, acc3 = 0.f;

    #pragma unroll
    for (int i = 0; i < K; ++i) {
        // issue all 7 nontemporal coeff loads for this neighbor row first
        f32x4 c4[K];
        #pragma unroll
        for (int j = 0; j < K; ++j)
            c4[j] = __builtin_nontemporal_load(
                reinterpret_cast<const f32x4*>(cptr + (i * K + j) * HW_));

        // sal cols (w4+1+c), c=0..9: covers j=0..6 for pixels p=0..3
        float row[K + 3];
        #pragma unroll
        for (int c = 0; c < K + 3; ++c)
            row[c] = sal[ty + i][w4 + 1 + c];

        #pragma unroll
        for (int j = 0; j < K; ++j) {
            acc0 = fmaf(row[j + 0], c4[j].x, acc0);
            acc1 = fmaf(row[j + 1], c4[j].y, acc1);
            acc2 = fmaf(row[j + 2], c4[j].z, acc2);
            acc3 = fmaf(row[j + 3], c4[j].w, acc3);
        }
    }

    f32x4 o;
    o.x = acc0; o.y = acc1; o.z = acc2; o.w = acc3;
    __builtin_nontemporal_store(
        o, reinterpret_cast<f32x4*>(out + base1 + (size_t)h * W_ + w4));
}

extern "C" void kernel_launch(void* const* d_in, const int* in_sizes, int n_in,
                              void* d_out, int out_size, void* d_ws, size_t ws_size,
                              hipStream_t stream) {
    const float* thick = (const float*)d_in[0];
    const float* thin  = (const float*)d_in[1];
    const float* coeff = (const float*)d_in[2];
    float* out = (float*)d_out;

    const int B = in_sizes[0] / HW_;       // 8

    dim3 grid(H_ / TH, B);                 // (64, 8) = 512 blocks
    dim3 block(128, 8);                    // 1024 threads = 16 waves

    hipLaunchKernelGGL(adaptive_aggregation_kernel, grid, block, 0, stream,
                       thick, thin, coeff, out);
}